// Round 1
// baseline (1004.194 us; speedup 1.0000x reference)
//
#include <hip/hip_runtime.h>
#include <math.h>

#define L_SEQ 8192
#define NFFT  16384
#define CCH   768
#define BB    4
#define EDIM  33
#define ODIM  64
#define BLK   512

// ---------- complex helpers ----------
__device__ __forceinline__ float2 cadd(float2 a, float2 b) { return make_float2(a.x + b.x, a.y + b.y); }
__device__ __forceinline__ float2 csub(float2 a, float2 b) { return make_float2(a.x - b.x, a.y - b.y); }
__device__ __forceinline__ float2 cmul(float2 a, float2 b) {
  return make_float2(fmaf(a.x, b.x, -a.y * b.y), fmaf(a.x, b.y, a.y * b.x));
}

// LDS bank-conflict swizzle: bijective, breaks power-of-2 strides.
__device__ __forceinline__ int swz(int i) { return i ^ ((i >> 4) & 15); }

// reverse 7 base-4 digits of a 14-bit index
__device__ __forceinline__ int rev4_14(int v) {
  int r = 0;
#pragma unroll
  for (int i = 0; i < 7; ++i) { r = (r << 2) | (v & 3); v >>= 2; }
  return r;
}

// ---------- kernel: twiddle table W_N^r = exp(-2*pi*i*r/N), r in [0, N) ----------
__global__ void twiddle_kernel(float2* __restrict__ tw) {
  int r = blockIdx.x * blockDim.x + threadIdx.x;
  if (r < NFFT) {
    float th = (float)(6.283185307179586476925286766559 / (double)NFFT) * (float)r;
    float s, c;
    sincosf(th, &s, &c);
    tw[r] = make_float2(c, -s);
  }
}

// ---------- kernel: implicit filter MLP + exponential modulation ----------
// k[c*L + l] = (MLP(z[l]) @ wout)[c] * exp(-t[l]*|deltas[c]|)
__global__ __launch_bounds__(256) void filter_kernel(
    const float* __restrict__ z,      // [L, 33]
    const float* __restrict__ t,      // [L]
    const float* __restrict__ deltas, // [C]
    const float* __restrict__ freq,   // [64]
    const float* __restrict__ w0, const float* __restrict__ b0,
    const float* __restrict__ w1, const float* __restrict__ b1,
    const float* __restrict__ w2, const float* __restrict__ b2,
    const float* __restrict__ wout,   // [64, C]
    float* __restrict__ k)            // [C, L]
{
  int l = blockIdx.x * blockDim.x + threadIdx.x;
  if (l >= L_SEQ) return;

  float zb[EDIM];
#pragma unroll
  for (int e = 0; e < EDIM; ++e) zb[e] = z[l * EDIM + e];

  float h[ODIM], hn[ODIM];
  for (int o = 0; o < ODIM; ++o) {
    float acc = b0[o];
#pragma unroll
    for (int e = 0; e < EDIM; ++e) acc = fmaf(zb[e], w0[e * ODIM + o], acc);
    h[o] = sinf(freq[o] * acc);
  }
  for (int o = 0; o < ODIM; ++o) {
    float acc = b1[o];
#pragma unroll
    for (int i = 0; i < ODIM; ++i) acc = fmaf(h[i], w1[i * ODIM + o], acc);
    hn[o] = sinf(freq[o] * acc);
  }
  for (int o = 0; o < ODIM; ++o) {
    float acc = b2[o];
#pragma unroll
    for (int i = 0; i < ODIM; ++i) acc = fmaf(hn[i], w2[i * ODIM + o], acc);
    h[o] = sinf(freq[o] * acc);
  }

  float tl = t[l];
  for (int c = 0; c < CCH; ++c) {
    float acc = 0.f;
#pragma unroll
    for (int o = 0; o < ODIM; ++o) acc = fmaf(h[o], wout[o * CCH + c], acc);
    float mod = expf(-tl * fabsf(deltas[c]));
    k[(size_t)c * L_SEQ + l] = acc * mod;
  }
}

// ---------- kernel: FFT convolution per (b,c) row ----------
// Packs Z = x + i*k, forward radix-4 DIF (natural -> base4-digit-reversed),
// spectral unpack+multiply in digit-reversed order, radix-4 DIT inverse
// (digit-reversed -> natural), out = Re(y) + x*bias.
__global__ __launch_bounds__(BLK) void conv_kernel(
    const float* __restrict__ x,    // [B*C, L]
    const float* __restrict__ kf,   // [C, L]
    const float* __restrict__ bias, // [C]
    const float2* __restrict__ tw,  // [NFFT]
    float* __restrict__ out)        // [B*C, L]
{
  extern __shared__ float2 Z[];  // NFFT entries (swizzled addressing)
  const int wg = blockIdx.x;     // = b*C + c
  const int c = wg % CCH;
  const int tid = threadIdx.x;
  const float* __restrict__ xr = x + (size_t)wg * L_SEQ;
  const float* __restrict__ kr = kf + (size_t)c * L_SEQ;

  // load: Z = x + i*k, zero-padded to 2L
#pragma unroll
  for (int i = tid; i < NFFT; i += BLK) {
    float re = 0.f, im = 0.f;
    if (i < L_SEQ) { re = xr[i]; im = kr[i]; }
    Z[swz(i)] = make_float2(re, im);
  }
  __syncthreads();

  // forward radix-4 DIF: stages m = 4096,1024,256,64,16,4,1
#pragma unroll
  for (int mlog = 12; mlog >= 0; mlog -= 2) {
    const int m = 1 << mlog;
    const int tstep = 1 << (12 - mlog);  // N/(4m)
#pragma unroll
    for (int j = tid; j < NFFT / 4; j += BLK) {
      const int u = j & (m - 1);
      const int i0 = ((j >> mlog) << (mlog + 2)) + u;
      float2 x0 = Z[swz(i0)];
      float2 x1 = Z[swz(i0 + m)];
      float2 x2 = Z[swz(i0 + 2 * m)];
      float2 x3 = Z[swz(i0 + 3 * m)];
      float2 a = cadd(x0, x2), b = csub(x0, x2);
      float2 cc = cadd(x1, x3), d = csub(x1, x3);
      float2 y0 = cadd(a, cc);
      float2 y2 = csub(a, cc);
      float2 t1 = make_float2(b.x + d.y, b.y - d.x);  // b - i*d
      float2 t3 = make_float2(b.x - d.y, b.y + d.x);  // b + i*d
      const int r = u * tstep;
      float2 w1 = tw[r];
      float2 w2 = cmul(w1, w1);
      float2 w3 = cmul(w2, w1);
      Z[swz(i0)]         = y0;
      Z[swz(i0 + m)]     = cmul(t1, w1);
      Z[swz(i0 + 2 * m)] = cmul(y2, w2);
      Z[swz(i0 + 3 * m)] = cmul(t3, w3);
    }
    __syncthreads();
  }

  // spectral unpack of the two packed real signals + pointwise multiply.
  // Position p holds bin rev4(p). Pair (f, N-f) processed by one thread.
  const float scale = 1.0f / (float)NFFT;
  for (int f = tid; f < NFFT / 2; f += BLK) {
    if (f == 0) {
      const int p0 = swz(0);
      const int pn = swz(rev4_14(NFFT / 2));
      float2 z0 = Z[p0];
      float2 zn = Z[pn];
      Z[p0] = make_float2(z0.x * z0.y * scale, 0.f);
      Z[pn] = make_float2(zn.x * zn.y * scale, 0.f);
    } else {
      const int p = swz(rev4_14(f));
      const int q = swz(rev4_14(NFFT - f));
      float2 zp = Z[p];
      float2 zq = Z[q];
      float2 X = make_float2(0.5f * (zp.x + zq.x), 0.5f * (zp.y - zq.y));
      float2 K = make_float2(0.5f * (zp.y + zq.y), -0.5f * (zp.x - zq.x));
      float2 Y = cmul(X, K);
      Y.x *= scale;
      Y.y *= scale;
      Z[p] = Y;
      Z[q] = make_float2(Y.x, -Y.y);
    }
  }
  __syncthreads();

  // inverse radix-4 DIT: stages m = 1,4,16,64,256,1024,4096
#pragma unroll
  for (int mlog = 0; mlog <= 12; mlog += 2) {
    const int m = 1 << mlog;
    const int tstep = 1 << (12 - mlog);
#pragma unroll
    for (int j = tid; j < NFFT / 4; j += BLK) {
      const int u = j & (m - 1);
      const int i0 = ((j >> mlog) << (mlog + 2)) + u;
      const int r = u * tstep;
      float2 w1f = tw[r];
      float2 w1 = make_float2(w1f.x, -w1f.y);  // conj -> e^{+i}
      float2 w2 = cmul(w1, w1);
      float2 w3 = cmul(w2, w1);
      float2 t0 = Z[swz(i0)];
      float2 t1 = cmul(Z[swz(i0 + m)], w1);
      float2 t2 = cmul(Z[swz(i0 + 2 * m)], w2);
      float2 t3 = cmul(Z[swz(i0 + 3 * m)], w3);
      float2 a = cadd(t0, t2), b = csub(t0, t2);
      float2 cc = cadd(t1, t3), d = csub(t1, t3);
      Z[swz(i0)]         = cadd(a, cc);
      Z[swz(i0 + m)]     = make_float2(b.x - d.y, b.y + d.x);  // b + i*d
      Z[swz(i0 + 2 * m)] = csub(a, cc);
      Z[swz(i0 + 3 * m)] = make_float2(b.x + d.y, b.y - d.x);  // b - i*d
    }
    __syncthreads();
  }

  // epilogue: y + x*bias
  const float bc = bias[c];
#pragma unroll
  for (int l = tid; l < L_SEQ; l += BLK) {
    out[(size_t)wg * L_SEQ + l] = Z[swz(l)].x + xr[l] * bc;
  }
}

extern "C" void kernel_launch(void* const* d_in, const int* in_sizes, int n_in,
                              void* d_out, int out_size, void* d_ws, size_t ws_size,
                              hipStream_t stream) {
  const float* x      = (const float*)d_in[0];
  const float* bias   = (const float*)d_in[1];
  const float* z      = (const float*)d_in[2];
  const float* t      = (const float*)d_in[3];
  const float* deltas = (const float*)d_in[4];
  const float* freq   = (const float*)d_in[5];
  const float* w0     = (const float*)d_in[6];
  const float* b0     = (const float*)d_in[7];
  const float* w1     = (const float*)d_in[8];
  const float* b1     = (const float*)d_in[9];
  const float* w2     = (const float*)d_in[10];
  const float* b2     = (const float*)d_in[11];
  const float* wout   = (const float*)d_in[12];
  float* out = (float*)d_out;

  // workspace layout: [twiddles 128 KB][k filter 24 MB]
  float2* tw = (float2*)d_ws;
  float* kfilt = (float*)((char*)d_ws + (size_t)NFFT * sizeof(float2));

  twiddle_kernel<<<NFFT / 256, 256, 0, stream>>>(tw);
  filter_kernel<<<L_SEQ / 256, 256, 0, stream>>>(z, t, deltas, freq,
                                                 w0, b0, w1, b1, w2, b2, wout, kfilt);

  hipFuncSetAttribute(reinterpret_cast<const void*>(conv_kernel),
                      hipFuncAttributeMaxDynamicSharedMemorySize,
                      NFFT * sizeof(float2));
  conv_kernel<<<BB * CCH, BLK, NFFT * sizeof(float2), stream>>>(x, kfilt, bias, tw, out);
}